// Round 1
// baseline (409.429 us; speedup 1.0000x reference)
//
#include <hip/hip_runtime.h>
#include <cmath>

// ---------------------------------------------------------------------------
// WireframeDetector: NMS -> top-k 300 junctions -> line sampling (bilinear +
// maxpool) -> 3-layer MLP (fp16 MFMA for the two 1024x1024 GEMMs).
// ---------------------------------------------------------------------------

typedef _Float16 f16;
typedef _Float16 f16x2 __attribute__((ext_vector_type(2)));
typedef _Float16 f16x8 __attribute__((ext_vector_type(8)));
typedef float f32x4 __attribute__((ext_vector_type(4)));

#define HWD 128
#define NPIX 16384            // 128*128
#define TOPK_N 300
#define NLINES 20000
#define MPAD 20096            // 157 * 128
#define KDIM 1024
#define NDIM 1024

// ---------------------------------------------------------------------------
// Transpose loi_features [C][H][W] fp32 -> loiT [H][W][C] fp16
// (channels contiguous so each bilinear tap is a coalesced 256B read)
// ---------------------------------------------------------------------------
__global__ __launch_bounds__(256) void transpose_loi_kernel(
    const float* __restrict__ loi, f16* __restrict__ loiT)
{
    int id = blockIdx.x * 256 + threadIdx.x;      // 2,097,152 total
    int x = id & 127;
    int c = (id >> 7) & 127;
    int y = id >> 14;
    float v = loi[c * NPIX + y * HWD + x];        // coalesced over x
    loiT[(y * HWD + x) * HWD + c] = (f16)v;       // scattered 2B, L2 absorbs
}

// ---------------------------------------------------------------------------
// Transpose W [K][N] fp32 -> Wt [N][K] fp16
// ---------------------------------------------------------------------------
__global__ __launch_bounds__(256) void transpose_w_kernel(
    const float* __restrict__ W, f16* __restrict__ Wt)
{
    int id = blockIdx.x * 256 + threadIdx.x;      // 1,048,576 total
    int n = id & 1023;                            // fast-varying -> coalesced read
    int k = id >> 10;
    float v = W[(size_t)k * NDIM + n];
    Wt[(size_t)n * KDIM + k] = (f16)v;
}

// ---------------------------------------------------------------------------
// NMS + exact top-k(300) + junction coords. Single block, 1024 threads.
// Key = (val_bits << 32) | (~pixel_idx): descending sort == value desc,
// index asc on ties — matches jax.lax.top_k stability.
// ---------------------------------------------------------------------------
__global__ __launch_bounds__(1024) void topk_junc_kernel(
    const float* __restrict__ jloc, const float* __restrict__ joff,
    float* __restrict__ juncs /* [300][2] (x,y) */)
{
    const int tid = threadIdx.x;
    __shared__ unsigned long long cand[4096];
    __shared__ int ncand;
    if (tid == 0) ncand = 0;
    __syncthreads();

    for (int t = 0; t < 16; ++t) {
        int p = t * 1024 + tid;
        int y = p >> 7, x = p & 127;
        float c = jloc[p];
        float m = c;
        for (int dy = -1; dy <= 1; ++dy) {
            int yy = y + dy;
            if (yy < 0 || yy >= HWD) continue;
            for (int dx = -1; dx <= 1; ++dx) {
                int xx = x + dx;
                if (xx < 0 || xx >= HWD) continue;
                m = fmaxf(m, jloc[yy * HWD + xx]);
            }
        }
        if (c == m && c > 0.0f) {   // NMS survivor (zeros can never reach top-300)
            int pos = atomicAdd(&ncand, 1);
            if (pos < 4096) {
                unsigned int ub = __float_as_uint(c);
                cand[pos] = ((unsigned long long)ub << 32) |
                            (unsigned long long)(0xFFFFFFFFu - (unsigned int)p);
            }
        }
    }
    __syncthreads();
    int n = ncand;
    for (int i = tid; i < 4096; i += 1024)
        if (i >= n) cand[i] = 0ULL;
    __syncthreads();

    // bitonic sort, descending, 4096 elements
    for (int k = 2; k <= 4096; k <<= 1) {
        for (int j = k >> 1; j > 0; j >>= 1) {
            for (int b = 0; b < 4; ++b) {
                int i = b * 1024 + tid;
                int ixj = i ^ j;
                if (ixj > i) {
                    unsigned long long vi = cand[i], vj = cand[ixj];
                    bool desc = ((i & k) == 0);
                    if (desc ? (vi < vj) : (vi > vj)) {
                        cand[i] = vj; cand[ixj] = vi;
                    }
                }
            }
            __syncthreads();
        }
    }

    if (tid < TOPK_N) {
        unsigned long long key = cand[tid];
        unsigned int p = 0xFFFFFFFFu - (unsigned int)(key & 0xFFFFFFFFull);
        // x = idx%w + (sigmoid(joff0)-0.5) + 0.5 = idx%w + sigmoid(joff0)
        float sx = 1.0f / (1.0f + expf(-joff[p]));
        float sy = 1.0f / (1.0f + expf(-joff[NPIX + p]));
        juncs[2 * tid + 0] = (float)(p & 127) + sx;
        juncs[2 * tid + 1] = (float)(p >> 7) + sy;
    }
}

// ---------------------------------------------------------------------------
// Per-line sampling: 32 pts bilinear over loiT[H][W][C], maxpool groups of 4,
// write fp16 feats row [l][c*8+p]. One wave per line; lane owns channels
// 2*lane, 2*lane+1.
// ---------------------------------------------------------------------------
__global__ __launch_bounds__(64) void sample_kernel(
    const f16* __restrict__ loiT, const float* __restrict__ juncs,
    const int* __restrict__ edge_idx, f16* __restrict__ feats)
{
    const int l = blockIdx.x;
    const int lane = threadIdx.x;
    const int e0 = edge_idx[2 * l], e1 = edge_idx[2 * l + 1];
    const float ux = juncs[2 * e0], uy = juncs[2 * e0 + 1];
    const float vx = juncs[2 * e1], vy = juncs[2 * e1 + 1];
    const int c2 = lane * 2;

    f16x8 o0, o1;
    #pragma unroll
    for (int p = 0; p < 8; ++p) {
        float m0 = -INFINITY, m1 = -INFINITY;
        #pragma unroll
        for (int jj = 0; jj < 4; ++jj) {
            const int j = p * 4 + jj;
            const float t = (float)j * (1.0f / 31.0f);
            const float px = ux * t + vx * (1.0f - t) - 0.5f;
            const float py = uy * t + vy * (1.0f - t) - 0.5f;
            float fx0 = fminf(fmaxf(floorf(px), 0.0f), 127.0f);
            float fy0 = fminf(fmaxf(floorf(py), 0.0f), 127.0f);
            float fx1 = fminf(fx0 + 1.0f, 127.0f);
            float fy1 = fminf(fy0 + 1.0f, 127.0f);
            int ix0 = (int)fx0, iy0 = (int)fy0, ix1 = (int)fx1, iy1 = (int)fy1;
            float w00 = (fy1 - py) * (fx1 - px);
            float w10 = (py - fy0) * (fx1 - px);
            float w01 = (fy1 - py) * (px - fx0);
            float w11 = (py - fy0) * (px - fx0);
            f16x2 v00 = *(const f16x2*)(loiT + (iy0 * HWD + ix0) * HWD + c2);
            f16x2 v10 = *(const f16x2*)(loiT + (iy1 * HWD + ix0) * HWD + c2);
            f16x2 v01 = *(const f16x2*)(loiT + (iy0 * HWD + ix1) * HWD + c2);
            f16x2 v11 = *(const f16x2*)(loiT + (iy1 * HWD + ix1) * HWD + c2);
            float s0 = (float)v00.x * w00 + (float)v10.x * w10 +
                       (float)v01.x * w01 + (float)v11.x * w11;
            float s1 = (float)v00.y * w00 + (float)v10.y * w10 +
                       (float)v01.y * w01 + (float)v11.y * w11;
            m0 = fmaxf(m0, s0);
            m1 = fmaxf(m1, s1);
        }
        o0[p] = (f16)m0;   // channel c2   -> feats[l, c2*8+p]   = 16*lane + p
        o1[p] = (f16)m1;   // channel c2+1 -> feats[l, c2*8+8+p] = 16*lane + 8 + p
    }
    f16* dst = feats + (size_t)l * KDIM + lane * 16;
    *(f16x8*)(dst) = o0;
    *(f16x8*)(dst + 8) = o1;
}

// ---------------------------------------------------------------------------
// GEMM: C[M][N] = relu(A[M][K] @ Bt[N][K]^T + bias), fp16 in, fp32 accum,
// fp16 out. 128x128 tile, BK=32, 256 threads (4 waves, 2x2 of 64x64),
// v_mfma_f32_16x16x32_f16.
// ---------------------------------------------------------------------------
__global__ __launch_bounds__(256, 2) void gemm_bias_relu_kernel(
    const f16* __restrict__ A, const f16* __restrict__ Bt,
    const float* __restrict__ bias, f16* __restrict__ C,
    int M, int N, int K, int relu)
{
    const int tid = threadIdx.x;
    const int wave = tid >> 6, lane = tid & 63;
    const int wm = wave >> 1, wn = wave & 1;
    const int m0 = blockIdx.x * 128;
    const int n0 = blockIdx.y * 128;

    __shared__ f16 sA[128 * 32];
    __shared__ f16 sB[128 * 32];

    f32x4 acc[4][4];
    #pragma unroll
    for (int mi = 0; mi < 4; ++mi)
        #pragma unroll
        for (int ni = 0; ni < 4; ++ni)
            acc[mi][ni] = (f32x4){0.f, 0.f, 0.f, 0.f};

    const int rowS = tid >> 2;           // 0..63
    const int chS = (tid & 3) * 8;       // fp16 offset of 16B chunk
    const int col16 = lane & 15;
    const int kq = (lane >> 4) * 8;

    for (int k0 = 0; k0 < K; k0 += 32) {
        const uint4 a0 = *(const uint4*)(A + (size_t)(m0 + rowS) * K + k0 + chS);
        const uint4 a1 = *(const uint4*)(A + (size_t)(m0 + rowS + 64) * K + k0 + chS);
        const uint4 b0 = *(const uint4*)(Bt + (size_t)(n0 + rowS) * K + k0 + chS);
        const uint4 b1 = *(const uint4*)(Bt + (size_t)(n0 + rowS + 64) * K + k0 + chS);
        __syncthreads();                 // previous iter's LDS reads done
        *(uint4*)(sA + rowS * 32 + chS) = a0;
        *(uint4*)(sA + (rowS + 64) * 32 + chS) = a1;
        *(uint4*)(sB + rowS * 32 + chS) = b0;
        *(uint4*)(sB + (rowS + 64) * 32 + chS) = b1;
        __syncthreads();

        f16x8 af[4], bf[4];
        #pragma unroll
        for (int i = 0; i < 4; ++i) {
            af[i] = *(const f16x8*)(sA + (wm * 64 + i * 16 + col16) * 32 + kq);
            bf[i] = *(const f16x8*)(sB + (wn * 64 + i * 16 + col16) * 32 + kq);
        }
        #pragma unroll
        for (int mi = 0; mi < 4; ++mi)
            #pragma unroll
            for (int ni = 0; ni < 4; ++ni)
                acc[mi][ni] = __builtin_amdgcn_mfma_f32_16x16x32_f16(
                    af[mi], bf[ni], acc[mi][ni], 0, 0, 0);
    }

    const int quad = lane >> 4;
    #pragma unroll
    for (int ni = 0; ni < 4; ++ni) {
        const int n = n0 + wn * 64 + ni * 16 + col16;
        const float b = bias[n];
        #pragma unroll
        for (int mi = 0; mi < 4; ++mi) {
            #pragma unroll
            for (int r = 0; r < 4; ++r) {
                const int m = m0 + wm * 64 + mi * 16 + quad * 4 + r;
                float v = acc[mi][ni][r] + b;
                if (relu) v = fmaxf(v, 0.f);
                C[(size_t)m * N + n] = (f16)v;
            }
        }
    }
}

// ---------------------------------------------------------------------------
// Head: out[l][j] = dot(h2[l], W3[:,j]) + b3[j]; one wave per line.
// ---------------------------------------------------------------------------
__global__ __launch_bounds__(64) void head_kernel(
    const f16* __restrict__ h2, const float* __restrict__ W3,
    const float* __restrict__ b3, float* __restrict__ out)
{
    const int l = blockIdx.x, lane = threadIdx.x;
    const f16* row = h2 + (size_t)l * KDIM + lane * 16;
    f16x8 r0 = *(const f16x8*)(row);
    f16x8 r1 = *(const f16x8*)(row + 8);
    float a0 = 0.f, a1 = 0.f, a2 = 0.f;
    #pragma unroll
    for (int u = 0; u < 16; ++u) {
        float h = (float)((u < 8) ? r0[u & 7] : r1[u & 7]);
        const float* w = W3 + (size_t)(lane * 16 + u) * 3;
        a0 += h * w[0];
        a1 += h * w[1];
        a2 += h * w[2];
    }
    #pragma unroll
    for (int off = 32; off > 0; off >>= 1) {
        a0 += __shfl_down(a0, off);
        a1 += __shfl_down(a1, off);
        a2 += __shfl_down(a2, off);
    }
    if (lane == 0) {
        out[l * 3 + 0] = a0 + b3[0];
        out[l * 3 + 1] = a1 + b3[1];
        out[l * 3 + 2] = a2 + b3[2];
    }
}

// ---------------------------------------------------------------------------
extern "C" void kernel_launch(void* const* d_in, const int* in_sizes, int n_in,
                              void* d_out, int out_size, void* d_ws, size_t ws_size,
                              hipStream_t stream)
{
    const float* jloc = (const float*)d_in[0];
    const float* joff = (const float*)d_in[1];
    const float* loi  = (const float*)d_in[2];
    const int*   eidx = (const int*)d_in[3];
    const float* W1   = (const float*)d_in[4];
    const float* b1   = (const float*)d_in[5];
    const float* W2   = (const float*)d_in[6];
    const float* b2   = (const float*)d_in[7];
    const float* W3   = (const float*)d_in[8];
    const float* b3   = (const float*)d_in[9];
    float* out = (float*)d_out;

    char* ws = (char*)d_ws;
    f16*   loiT  = (f16*)(ws);                          // 4 MB
    f16*   W1T   = (f16*)(ws + ((size_t)4 << 20));      // 2 MB
    f16*   W2T   = (f16*)(ws + ((size_t)6 << 20));      // 2 MB
    float* juncs = (float*)(ws + ((size_t)8 << 20));    // 2.4 KB
    f16*   feats = (f16*)(ws + ((size_t)9 << 20));      // 39.3 MB (MPAD x 1024)
    f16*   h1    = (f16*)(ws + ((size_t)50 << 20));     // 39.3 MB
    f16*   h2    = feats;                               // reuse: feats dead after GEMM1

    transpose_loi_kernel<<<dim3(8192), dim3(256), 0, stream>>>(loi, loiT);
    transpose_w_kernel<<<dim3(4096), dim3(256), 0, stream>>>(W1, W1T);
    transpose_w_kernel<<<dim3(4096), dim3(256), 0, stream>>>(W2, W2T);
    topk_junc_kernel<<<dim3(1), dim3(1024), 0, stream>>>(jloc, joff, juncs);
    sample_kernel<<<dim3(NLINES), dim3(64), 0, stream>>>(loiT, juncs, eidx, feats);
    gemm_bias_relu_kernel<<<dim3(MPAD / 128, NDIM / 128), dim3(256), 0, stream>>>(
        feats, W1T, b1, h1, MPAD, NDIM, KDIM, 1);
    gemm_bias_relu_kernel<<<dim3(MPAD / 128, NDIM / 128), dim3(256), 0, stream>>>(
        h1, W2T, b2, h2, MPAD, NDIM, KDIM, 1);
    head_kernel<<<dim3(NLINES), dim3(64), 0, stream>>>(h2, W3, b3, out);
}

// Round 2
// 361.979 us; speedup vs baseline: 1.1311x; 1.1311x over previous
//
#include <hip/hip_runtime.h>
#include <cmath>

// ---------------------------------------------------------------------------
// WireframeDetector: NMS -> top-k 300 junctions -> line sampling (bilinear +
// maxpool) -> 3-layer MLP (fp16 MFMA for the two 1024x1024 GEMMs).
// R1: global_load_lds GEMM staging (m97 structure), split NMS from sort,
//     LDS-tiled transposes, 256-thread sample/head blocks.
// ---------------------------------------------------------------------------

typedef _Float16 f16;
typedef _Float16 f16x2 __attribute__((ext_vector_type(2)));
typedef _Float16 f16x8 __attribute__((ext_vector_type(8)));
typedef float f32x4 __attribute__((ext_vector_type(4)));

#define HWD 128
#define NPIX 16384            // 128*128
#define TOPK_N 300
#define NLINES 20000
#define MPAD 20096            // 157 * 128
#define KDIM 1024
#define NDIM 1024
#define MAXCAND 4096

// async global->LDS, 16B per lane; LDS dest = wave-uniform base + lane*16
#define G2L(gp, lp) __builtin_amdgcn_global_load_lds( \
    (const __attribute__((address_space(1))) void*)(gp), \
    (__attribute__((address_space(3))) void*)(lp), 16, 0, 0)

// ---------------------------------------------------------------------------
// Transpose loi_features [C][H][W] fp32 -> loiT [H][W][C] fp16, LDS-tiled.
// One block per y-row; coalesced reads over x, f16x8 coalesced writes.
// Side job: block 0 zeros the NMS candidate counter.
// ---------------------------------------------------------------------------
__global__ __launch_bounds__(256) void transpose_loi_kernel(
    const float* __restrict__ loi, f16* __restrict__ loiT, int* __restrict__ count)
{
    if (blockIdx.x == 0 && threadIdx.x == 0) *count = 0;
    __shared__ f16 t[128 * 130];     // [x][c], +2 pad breaks bank conflicts
    const int y = blockIdx.x;        // 128 blocks
    const int tid = threadIdx.x;
    #pragma unroll 4
    for (int it = 0; it < 64; ++it) {
        int idx = it * 256 + tid;    // c-major, x fast -> coalesced read
        int c = idx >> 7, x = idx & 127;
        t[x * 130 + c] = (f16)loi[c * NPIX + y * HWD + x];
    }
    __syncthreads();
    #pragma unroll
    for (int it = 0; it < 8; ++it) {
        int j = it * 256 + tid;      // 2048 chunks of 8 f16
        int x = j >> 4, cc = (j & 15) * 8;
        f16x8 v;
        #pragma unroll
        for (int u = 0; u < 8; ++u) v[u] = t[x * 130 + cc + u];
        *(f16x8*)(loiT + (y * HWD + x) * HWD + cc) = v;
    }
}

// ---------------------------------------------------------------------------
// Transpose W [K][N] fp32 -> Wt [N][K] fp16, 64x64 LDS tiles.
// ---------------------------------------------------------------------------
__global__ __launch_bounds__(256) void transpose_w_kernel(
    const float* __restrict__ W, f16* __restrict__ Wt)
{
    __shared__ f16 t[64 * 66];
    const int k0 = (blockIdx.x >> 4) * 64;
    const int n0 = (blockIdx.x & 15) * 64;
    const int tid = threadIdx.x;
    #pragma unroll 4
    for (int it = 0; it < 16; ++it) {
        int i = it * 256 + tid;      // 4096: r=k-offset, c=n-offset (coalesced)
        int r = i >> 6, c = i & 63;
        t[c * 66 + r] = (f16)W[(size_t)(k0 + r) * NDIM + n0 + c];
    }
    __syncthreads();
    #pragma unroll
    for (int it = 0; it < 2; ++it) {
        int j = it * 256 + tid;      // 512 chunks of 8 f16
        int nr = j >> 3, kc = (j & 7) * 8;
        f16x8 v;
        #pragma unroll
        for (int u = 0; u < 8; ++u) v[u] = t[nr * 66 + kc + u];
        *(f16x8*)(Wt + (size_t)(n0 + nr) * KDIM + k0 + kc) = v;
    }
}

// ---------------------------------------------------------------------------
// NMS scan, multi-block: survivors -> global candidate list.
// Key = (val_bits << 32) | (~pixel_idx): desc sort == value desc, index asc.
// ---------------------------------------------------------------------------
__global__ __launch_bounds__(256) void nms_kernel(
    const float* __restrict__ jloc, unsigned long long* __restrict__ cand,
    int* __restrict__ count)
{
    const int p = blockIdx.x * 256 + threadIdx.x;   // 64 blocks
    const int y = p >> 7, x = p & 127;
    const float c = jloc[p];
    float m = c;
    for (int dy = -1; dy <= 1; ++dy) {
        int yy = y + dy;
        if (yy < 0 || yy >= HWD) continue;
        for (int dx = -1; dx <= 1; ++dx) {
            int xx = x + dx;
            if (xx < 0 || xx >= HWD) continue;
            m = fmaxf(m, jloc[yy * HWD + xx]);
        }
    }
    if (c == m && c > 0.0f) {
        int pos = atomicAdd(count, 1);
        if (pos < MAXCAND) {
            unsigned int ub = __float_as_uint(c);
            cand[pos] = ((unsigned long long)ub << 32) |
                        (unsigned long long)(0xFFFFFFFFu - (unsigned int)p);
        }
    }
}

// ---------------------------------------------------------------------------
// Single-block bitonic sort of candidates (desc) + junction coords.
// ---------------------------------------------------------------------------
__global__ __launch_bounds__(1024) void topk_sort_kernel(
    const unsigned long long* __restrict__ gcand, const int* __restrict__ count,
    const float* __restrict__ joff, float* __restrict__ juncs /* [300][2] */)
{
    const int tid = threadIdx.x;
    __shared__ unsigned long long cand[MAXCAND];
    const int n = min(*count, MAXCAND);
    for (int i = tid; i < MAXCAND; i += 1024)
        cand[i] = (i < n) ? gcand[i] : 0ULL;
    __syncthreads();

    for (int k = 2; k <= MAXCAND; k <<= 1) {
        for (int j = k >> 1; j > 0; j >>= 1) {
            #pragma unroll
            for (int b = 0; b < 4; ++b) {
                int i = b * 1024 + tid;
                int ixj = i ^ j;
                if (ixj > i) {
                    unsigned long long vi = cand[i], vj = cand[ixj];
                    bool desc = ((i & k) == 0);
                    if (desc ? (vi < vj) : (vi > vj)) {
                        cand[i] = vj; cand[ixj] = vi;
                    }
                }
            }
            __syncthreads();
        }
    }

    if (tid < TOPK_N) {
        unsigned long long key = cand[tid];
        unsigned int p = 0xFFFFFFFFu - (unsigned int)(key & 0xFFFFFFFFull);
        // x = idx%w + (sigmoid(joff0)-0.5) + 0.5 = idx%w + sigmoid(joff0)
        float sx = 1.0f / (1.0f + expf(-joff[p]));
        float sy = 1.0f / (1.0f + expf(-joff[NPIX + p]));
        juncs[2 * tid + 0] = (float)(p & 127) + sx;
        juncs[2 * tid + 1] = (float)(p >> 7) + sy;
    }
}

// ---------------------------------------------------------------------------
// Per-line sampling: 32 pts bilinear over loiT[H][W][C], maxpool groups of 4,
// write fp16 feats row. 4 lines/block; lane owns channels 2*lane, 2*lane+1.
// ---------------------------------------------------------------------------
__global__ __launch_bounds__(256) void sample_kernel(
    const f16* __restrict__ loiT, const float* __restrict__ juncs,
    const int* __restrict__ edge_idx, f16* __restrict__ feats)
{
    const int l = blockIdx.x * 4 + (threadIdx.x >> 6);
    const int lane = threadIdx.x & 63;
    const int e0 = edge_idx[2 * l], e1 = edge_idx[2 * l + 1];
    const float ux = juncs[2 * e0], uy = juncs[2 * e0 + 1];
    const float vx = juncs[2 * e1], vy = juncs[2 * e1 + 1];
    const int c2 = lane * 2;

    f16x8 o0, o1;
    #pragma unroll
    for (int p = 0; p < 8; ++p) {
        float m0 = -INFINITY, m1 = -INFINITY;
        #pragma unroll
        for (int jj = 0; jj < 4; ++jj) {
            const int j = p * 4 + jj;
            const float t = (float)j * (1.0f / 31.0f);
            const float px = ux * t + vx * (1.0f - t) - 0.5f;
            const float py = uy * t + vy * (1.0f - t) - 0.5f;
            float fx0 = fminf(fmaxf(floorf(px), 0.0f), 127.0f);
            float fy0 = fminf(fmaxf(floorf(py), 0.0f), 127.0f);
            float fx1 = fminf(fx0 + 1.0f, 127.0f);
            float fy1 = fminf(fy0 + 1.0f, 127.0f);
            int ix0 = (int)fx0, iy0 = (int)fy0, ix1 = (int)fx1, iy1 = (int)fy1;
            float w00 = (fy1 - py) * (fx1 - px);
            float w10 = (py - fy0) * (fx1 - px);
            float w01 = (fy1 - py) * (px - fx0);
            float w11 = (py - fy0) * (px - fx0);
            f16x2 v00 = *(const f16x2*)(loiT + (iy0 * HWD + ix0) * HWD + c2);
            f16x2 v10 = *(const f16x2*)(loiT + (iy1 * HWD + ix0) * HWD + c2);
            f16x2 v01 = *(const f16x2*)(loiT + (iy0 * HWD + ix1) * HWD + c2);
            f16x2 v11 = *(const f16x2*)(loiT + (iy1 * HWD + ix1) * HWD + c2);
            float s0 = (float)v00.x * w00 + (float)v10.x * w10 +
                       (float)v01.x * w01 + (float)v11.x * w11;
            float s1 = (float)v00.y * w00 + (float)v10.y * w10 +
                       (float)v01.y * w01 + (float)v11.y * w11;
            m0 = fmaxf(m0, s0);
            m1 = fmaxf(m1, s1);
        }
        o0[p] = (f16)m0;   // channel c2   -> feats[l, 16*lane + p]
        o1[p] = (f16)m1;   // channel c2+1 -> feats[l, 16*lane + 8 + p]
    }
    f16* dst = feats + (size_t)l * KDIM + lane * 16;
    *(f16x8*)(dst) = o0;
    *(f16x8*)(dst + 8) = o1;
}

// ---------------------------------------------------------------------------
// GEMM: C[M][N] = relu(A[M][K] @ Bt[N][K]^T + bias), fp16 in, fp32 accum,
// fp16 out. 128x128 tile, BK=32, 256 threads (2x2 waves of 64x64 subtiles),
// m97 structure: global_load_lds dwordx4 staging + 16x16x32 MFMA.
// ---------------------------------------------------------------------------
__global__ __launch_bounds__(256, 2) void gemm_bias_relu_kernel(
    const f16* __restrict__ A, const f16* __restrict__ Bt,
    const float* __restrict__ bias, f16* __restrict__ C,
    int M, int N, int K, int relu)
{
    const int tid = threadIdx.x;
    const int wave = tid >> 6, lane = tid & 63;
    const int wm = wave >> 1, wn = wave & 1;
    const int m0 = blockIdx.x * 128;
    const int n0 = blockIdx.y * 128;

    __shared__ f16 sA[128 * 32];
    __shared__ f16 sB[128 * 32];

    f32x4 acc[4][4];
    #pragma unroll
    for (int mi = 0; mi < 4; ++mi)
        #pragma unroll
        for (int ni = 0; ni < 4; ++ni)
            acc[mi][ni] = (f32x4){0.f, 0.f, 0.f, 0.f};

    // DMA staging: 16 KB/iter = 16 segments of 1KB; wave w owns A-seg {w,w+4}
    // and B-seg {w,w+4}. Lane i covers row seg*16+(i>>2), 16B chunk i&3.
    const int rs0 = wave * 16 + (lane >> 2);
    const int rs1 = rs0 + 64;
    const int kc = (lane & 3) * 8;
    const f16* gA0 = A + (size_t)(m0 + rs0) * K + kc;
    const f16* gA1 = A + (size_t)(m0 + rs1) * K + kc;
    const f16* gB0 = Bt + (size_t)(n0 + rs0) * K + kc;
    const f16* gB1 = Bt + (size_t)(n0 + rs1) * K + kc;
    f16* lA0 = sA + wave * 512;          // + lane*16B implicit
    f16* lA1 = sA + (wave + 4) * 512;
    f16* lB0 = sB + wave * 512;
    f16* lB1 = sB + (wave + 4) * 512;

    const int col16 = lane & 15;
    const int kq = (lane >> 4) * 8;

    for (int k0 = 0; k0 < K; k0 += 32) {
        __syncthreads();                 // prev iter's LDS reads complete
        G2L(gA0 + k0, lA0);
        G2L(gA1 + k0, lA1);
        G2L(gB0 + k0, lB0);
        G2L(gB1 + k0, lB1);
        __builtin_amdgcn_s_waitcnt(0x0f70);   // vmcnt(0): own DMA done
        __syncthreads();                      // all waves' DMA done

        f16x8 af[4], bf[4];
        #pragma unroll
        for (int i = 0; i < 4; ++i) {
            af[i] = *(const f16x8*)(sA + (wm * 64 + i * 16 + col16) * 32 + kq);
            bf[i] = *(const f16x8*)(sB + (wn * 64 + i * 16 + col16) * 32 + kq);
        }
        #pragma unroll
        for (int mi = 0; mi < 4; ++mi)
            #pragma unroll
            for (int ni = 0; ni < 4; ++ni)
                acc[mi][ni] = __builtin_amdgcn_mfma_f32_16x16x32_f16(
                    af[mi], bf[ni], acc[mi][ni], 0, 0, 0);
    }

    const int quad = lane >> 4;
    #pragma unroll
    for (int ni = 0; ni < 4; ++ni) {
        const int n = n0 + wn * 64 + ni * 16 + col16;
        const float b = bias[n];
        #pragma unroll
        for (int mi = 0; mi < 4; ++mi) {
            #pragma unroll
            for (int r = 0; r < 4; ++r) {
                const int m = m0 + wm * 64 + mi * 16 + quad * 4 + r;
                float v = acc[mi][ni][r] + b;
                if (relu) v = fmaxf(v, 0.f);
                C[(size_t)m * N + n] = (f16)v;
            }
        }
    }
}

// ---------------------------------------------------------------------------
// Head: out[l][j] = dot(h2[l], W3[:,j]) + b3[j]; 4 lines/block, wave/line.
// ---------------------------------------------------------------------------
__global__ __launch_bounds__(256) void head_kernel(
    const f16* __restrict__ h2, const float* __restrict__ W3,
    const float* __restrict__ b3, float* __restrict__ out)
{
    const int l = blockIdx.x * 4 + (threadIdx.x >> 6);
    const int lane = threadIdx.x & 63;
    const f16* row = h2 + (size_t)l * KDIM + lane * 16;
    f16x8 r0 = *(const f16x8*)(row);
    f16x8 r1 = *(const f16x8*)(row + 8);
    float a0 = 0.f, a1 = 0.f, a2 = 0.f;
    #pragma unroll
    for (int u = 0; u < 16; ++u) {
        float h = (float)((u < 8) ? r0[u & 7] : r1[u & 7]);
        const float* w = W3 + (size_t)(lane * 16 + u) * 3;
        a0 += h * w[0];
        a1 += h * w[1];
        a2 += h * w[2];
    }
    #pragma unroll
    for (int off = 32; off > 0; off >>= 1) {
        a0 += __shfl_down(a0, off);
        a1 += __shfl_down(a1, off);
        a2 += __shfl_down(a2, off);
    }
    if (lane == 0) {
        out[l * 3 + 0] = a0 + b3[0];
        out[l * 3 + 1] = a1 + b3[1];
        out[l * 3 + 2] = a2 + b3[2];
    }
}

// ---------------------------------------------------------------------------
extern "C" void kernel_launch(void* const* d_in, const int* in_sizes, int n_in,
                              void* d_out, int out_size, void* d_ws, size_t ws_size,
                              hipStream_t stream)
{
    const float* jloc = (const float*)d_in[0];
    const float* joff = (const float*)d_in[1];
    const float* loi  = (const float*)d_in[2];
    const int*   eidx = (const int*)d_in[3];
    const float* W1   = (const float*)d_in[4];
    const float* b1   = (const float*)d_in[5];
    const float* W2   = (const float*)d_in[6];
    const float* b2   = (const float*)d_in[7];
    const float* W3   = (const float*)d_in[8];
    const float* b3   = (const float*)d_in[9];
    float* out = (float*)d_out;

    char* ws = (char*)d_ws;
    f16*   loiT  = (f16*)(ws);                            // 4 MB
    f16*   W1T   = (f16*)(ws + ((size_t)4 << 20));        // 2 MB
    f16*   W2T   = (f16*)(ws + ((size_t)6 << 20));        // 2 MB
    float* juncs = (float*)(ws + ((size_t)8 << 20));      // 2.4 KB
    int*   count = (int*)(ws + ((size_t)8 << 20) + 4096);
    unsigned long long* cand =
        (unsigned long long*)(ws + ((size_t)8 << 20) + 8192);  // 32 KB
    f16*   feats = (f16*)(ws + ((size_t)9 << 20));        // 39.3 MB (MPAD x 1024)
    f16*   h1    = (f16*)(ws + ((size_t)50 << 20));       // 39.3 MB
    f16*   h2    = feats;                                 // feats dead after GEMM1

    transpose_loi_kernel<<<dim3(HWD), dim3(256), 0, stream>>>(loi, loiT, count);
    transpose_w_kernel<<<dim3(256), dim3(256), 0, stream>>>(W1, W1T);
    transpose_w_kernel<<<dim3(256), dim3(256), 0, stream>>>(W2, W2T);
    nms_kernel<<<dim3(64), dim3(256), 0, stream>>>(jloc, cand, count);
    topk_sort_kernel<<<dim3(1), dim3(1024), 0, stream>>>(cand, count, joff, juncs);
    sample_kernel<<<dim3(NLINES / 4), dim3(256), 0, stream>>>(loiT, juncs, eidx, feats);
    gemm_bias_relu_kernel<<<dim3(MPAD / 128, NDIM / 128), dim3(256), 0, stream>>>(
        feats, W1T, b1, h1, MPAD, NDIM, KDIM, 1);
    gemm_bias_relu_kernel<<<dim3(MPAD / 128, NDIM / 128), dim3(256), 0, stream>>>(
        h1, W2T, b2, h2, MPAD, NDIM, KDIM, 1);
    head_kernel<<<dim3(NLINES / 4), dim3(256), 0, stream>>>(h2, W3, b3, out);
}